// Round 1
// baseline (311.511 us; speedup 1.0000x reference)
//
#include <hip/hip_runtime.h>
#include <hip/hip_bf16.h>
#include <math.h>

// Problem constants (from setup_inputs): B=8192, E=16, H=1024
#define B_SZ 8192
#define H_SZ 1024
#define E_SZ 16
#define NT   64      // 8192 / 128 tiles per dimension
#define BM   128     // tile rows/cols
#define BK   32      // K-step (matches MFMA K)
#define LDA  40      // padded LDS row stride (bf16 elems): 80B -> 2-way bank alias (free)
#define SIM_THR 0.8f

typedef __bf16 bf16_t;
typedef __bf16 bf16x8 __attribute__((ext_vector_type(8)));
typedef __bf16 bf16x4 __attribute__((ext_vector_type(4)));
typedef float  floatx4 __attribute__((ext_vector_type(4)));

// ---------------- workspace layout (byte offsets into d_ws) ----------------
// 0        : float  gsum
// 4        : uint   gcnt
// 4096     : float  ne[8192]
// 65536    : float  L[8192*16]
// 589824+  : float  P[8192*16]   (placed at 65536+524288)
// 2097152  : bf16   emb_n[8192*1024]  (16 MB)
#define OFF_NE   4096
#define OFF_L    65536
#define OFF_P    (65536 + 524288)
#define OFF_EMB  2097152

// ---------------------------------------------------------------------------
// Kernel 1: per-row log_softmax / softmax / negative entropy. One thread/row.
// Thread (0,0) also zero-inits the global accumulators (stream-ordered before
// the main kernel, so this is graph-capture safe).
// ---------------------------------------------------------------------------
__global__ void softmax_prep(const float* __restrict__ rp,
                             float* __restrict__ L, float* __restrict__ P,
                             float* __restrict__ ne,
                             float* __restrict__ gsum, unsigned int* __restrict__ gcnt) {
    int i = blockIdx.x * blockDim.x + threadIdx.x;
    if (i == 0) { *gsum = 0.f; *gcnt = 0u; }
    if (i >= B_SZ) return;
    const float* x = rp + i * E_SZ;
    float v[E_SZ];
    float m = -INFINITY;
#pragma unroll
    for (int k = 0; k < E_SZ; k++) { v[k] = x[k]; m = fmaxf(m, v[k]); }
    float s = 0.f;
#pragma unroll
    for (int k = 0; k < E_SZ; k++) s += expf(v[k] - m);
    float lse = m + logf(s);
    float nent = 0.f;
#pragma unroll
    for (int k = 0; k < E_SZ; k++) {
        float l = v[k] - lse;
        float p = expf(l);
        L[i * E_SZ + k] = l;
        P[i * E_SZ + k] = p;
        nent += p * l;
    }
    ne[i] = nent;
}

// ---------------------------------------------------------------------------
// Kernel 2: L2-normalize each embedding row and convert to bf16.
// One wave (64 lanes) per row; 16 floats/lane as 4x float4.
// ---------------------------------------------------------------------------
__global__ void normalize_emb(const float* __restrict__ emb, bf16_t* __restrict__ out) {
    int gwave = (blockIdx.x * blockDim.x + threadIdx.x) >> 6;
    int lane  = threadIdx.x & 63;
    if (gwave >= B_SZ) return;
    const float4* row = (const float4*)(emb + (size_t)gwave * H_SZ);
    float4 v[4];
    float ss = 0.f;
#pragma unroll
    for (int p = 0; p < 4; p++) {
        v[p] = row[p * 64 + lane];
        ss += v[p].x * v[p].x + v[p].y * v[p].y + v[p].z * v[p].z + v[p].w * v[p].w;
    }
#pragma unroll
    for (int off = 32; off > 0; off >>= 1) ss += __shfl_down(ss, off, 64);
    ss = __shfl(ss, 0, 64);
    float inv = rsqrtf(ss);
    bf16x4* orow = (bf16x4*)(out + (size_t)gwave * H_SZ);
#pragma unroll
    for (int p = 0; p < 4; p++) {
        bf16x4 o;
        o.x = (__bf16)(v[p].x * inv);
        o.y = (__bf16)(v[p].y * inv);
        o.z = (__bf16)(v[p].z * inv);
        o.w = (__bf16)(v[p].w * inv);
        orow[p * 64 + lane] = o;
    }
}

// g(r) = number of upper-triangle tiles in rows < r  (row r has NT-r tiles)
__device__ __forceinline__ int tri_g(int r) { return r * (2 * NT + 1 - r) / 2; }

// ---------------------------------------------------------------------------
// Kernel 3: main. Upper-triangle 128x128 sim tiles via bf16 MFMA; fused mask
// + KL accumulate. Off-diagonal tiles account both (i,j) and (j,i).
// 256 threads = 4 waves, each wave computes a 64x64 quadrant (4x4 frags).
// ---------------------------------------------------------------------------
__global__ __launch_bounds__(256)
void sim_kl_kernel(const bf16_t* __restrict__ emb,
                   const float* __restrict__ Lm, const float* __restrict__ Pm,
                   const float* __restrict__ ne,
                   float* __restrict__ gsum, unsigned int* __restrict__ gcnt) {
    __shared__ __align__(16) bf16_t As[BM * LDA];
    __shared__ __align__(16) bf16_t Bs[BM * LDA];
    __shared__ float redf[4];
    __shared__ unsigned int redc[4];

    // --- linear block id -> (bi, bj) with bj >= bi ---
    int t = blockIdx.x;
    float disc = (float)((2 * NT + 1) * (2 * NT + 1) - 8 * t);
    int bi = (int)(((float)(2 * NT + 1) - sqrtf(disc)) * 0.5f);
    if (bi < 0) bi = 0;
    if (bi > NT - 1) bi = NT - 1;
    while (bi + 1 <= NT - 1 && tri_g(bi + 1) <= t) bi++;
    while (bi > 0 && tri_g(bi) > t) bi--;
    int bj = bi + (t - tri_g(bi));
    const bool diag = (bi == bj);
    const int rowI = bi * BM, rowJ = bj * BM;

    const int tid  = threadIdx.x;
    const int lane = tid & 63;
    const int wave = tid >> 6;
    const int wr = (wave >> 1) * 64;   // wave quadrant row
    const int wc = (wave & 1) * 64;    // wave quadrant col
    const int quad = lane >> 4;
    const int l16  = lane & 15;

    floatx4 acc[4][4];
#pragma unroll
    for (int mi = 0; mi < 4; mi++)
#pragma unroll
        for (int ni = 0; ni < 4; ni++) {
            floatx4 z = {0.f, 0.f, 0.f, 0.f};
            acc[mi][ni] = z;
        }

    // staging: 256 threads, 4 threads/row (16B each), 64 rows/pass, 2 passes
    const int srow = tid >> 2;        // 0..63
    const int scol = (tid & 3) * 8;   // bf16 element offset {0,8,16,24}
    const bf16_t* gA = emb + (size_t)(rowI + srow) * H_SZ + scol;
    const bf16_t* gB = emb + (size_t)(rowJ + srow) * H_SZ + scol;

    for (int kt = 0; kt < H_SZ / BK; kt++) {
        const int k0 = kt * BK;
        uint4 a0 = *(const uint4*)(gA + k0);
        uint4 a1 = *(const uint4*)(gA + (size_t)64 * H_SZ + k0);
        uint4 b0 = *(const uint4*)(gB + k0);
        uint4 b1 = *(const uint4*)(gB + (size_t)64 * H_SZ + k0);
        __syncthreads();
        *(uint4*)(As + srow * LDA + scol)        = a0;
        *(uint4*)(As + (srow + 64) * LDA + scol) = a1;
        *(uint4*)(Bs + srow * LDA + scol)        = b0;
        *(uint4*)(Bs + (srow + 64) * LDA + scol) = b1;
        __syncthreads();

        bf16x8 af[4], bfr[4];
#pragma unroll
        for (int mi = 0; mi < 4; mi++)
            af[mi] = *(const bf16x8*)(As + (wr + mi * 16 + l16) * LDA + quad * 8);
#pragma unroll
        for (int ni = 0; ni < 4; ni++)
            bfr[ni] = *(const bf16x8*)(Bs + (wc + ni * 16 + l16) * LDA + quad * 8);
#pragma unroll
        for (int mi = 0; mi < 4; mi++)
#pragma unroll
            for (int ni = 0; ni < 4; ni++)
                acc[mi][ni] = __builtin_amdgcn_mfma_f32_16x16x32_bf16(
                    af[mi], bfr[ni], acc[mi][ni], 0, 0, 0);
    }

    // --- epilogue: masked KL accumulate ---
    // C/D layout (16x16x32): col = lane&15, row = (lane>>4)*4 + reg
    float fsum = 0.f;
    unsigned int lcnt = 0;
#pragma unroll
    for (int mi = 0; mi < 4; mi++) {
#pragma unroll
        for (int ni = 0; ni < 4; ni++) {
#pragma unroll
            for (int r = 0; r < 4; r++) {
                int i = rowI + wr + mi * 16 + quad * 4 + r;
                int j = rowJ + wc + ni * 16 + l16;
                float sim = acc[mi][ni][r];
                if (sim > SIM_THR && i != j) {
                    const float* Li = Lm + i * E_SZ;
                    const float* Pj = Pm + j * E_SZ;
                    float d = 0.f;
#pragma unroll
                    for (int k = 0; k < E_SZ; k++) d += Li[k] * Pj[k];
                    float s = ne[j] - d;
                    if (!diag) {
                        const float* Lj = Lm + j * E_SZ;
                        const float* Pi = Pm + i * E_SZ;
                        float d2 = 0.f;
#pragma unroll
                        for (int k = 0; k < E_SZ; k++) d2 += Lj[k] * Pi[k];
                        s += ne[i] - d2;
                        lcnt += 2;
                    } else {
                        lcnt += 1;
                    }
                    fsum += s;
                }
            }
        }
    }

    // block reduction: wave shuffle, then 4 partials via LDS, one atomic each
#pragma unroll
    for (int off = 32; off > 0; off >>= 1) {
        fsum += __shfl_down(fsum, off, 64);
        lcnt += __shfl_down(lcnt, off, 64);
    }
    if (lane == 0) { redf[wave] = fsum; redc[wave] = lcnt; }
    __syncthreads();
    if (tid == 0) {
        float s = redf[0] + redf[1] + redf[2] + redf[3];
        unsigned int c = redc[0] + redc[1] + redc[2] + redc[3];
        if (c > 0u) {
            atomicAdd(gsum, s);
            atomicAdd(gcnt, c);
        }
    }
}

// ---------------------------------------------------------------------------
// Kernel 4: finalize scalar output.
// ---------------------------------------------------------------------------
__global__ void finalize_out(const float* __restrict__ gsum,
                             const unsigned int* __restrict__ gcnt,
                             float* __restrict__ out) {
    unsigned int c = *gcnt;
    out[0] = (c > 0u) ? (*gsum / (float)c) : 0.f;   // WEIGHT = 1.0
}

// ---------------------------------------------------------------------------
extern "C" void kernel_launch(void* const* d_in, const int* in_sizes, int n_in,
                              void* d_out, int out_size, void* d_ws, size_t ws_size,
                              hipStream_t stream) {
    const float* rp  = (const float*)d_in[0];   // routing_probs [8192,16] f32
    const float* emb = (const float*)d_in[1];   // input_embeddings [8192,1024] f32
    float* out = (float*)d_out;

    char* ws = (char*)d_ws;
    float*        gsum = (float*)(ws + 0);
    unsigned int* gcnt = (unsigned int*)(ws + 4);
    float*        ne   = (float*)(ws + OFF_NE);
    float*        Lm   = (float*)(ws + OFF_L);
    float*        Pm   = (float*)(ws + OFF_P);
    bf16_t*       embb = (bf16_t*)(ws + OFF_EMB);

    softmax_prep<<<B_SZ / 256, 256, 0, stream>>>(rp, Lm, Pm, ne, gsum, gcnt);
    normalize_emb<<<B_SZ / 4, 256, 0, stream>>>(emb, embb);  // 4 waves/block, 1 row/wave
    const int ntri = NT * (NT + 1) / 2;  // 2080 upper-triangle tiles
    sim_kl_kernel<<<ntri, 256, 0, stream>>>(embb, Lm, Pm, ne, gsum, gcnt);
    finalize_out<<<1, 1, 0, stream>>>(gsum, gcnt, out);
}